// Round 7
// baseline (232.426 us; speedup 1.0000x reference)
//
#include <hip/hip_runtime.h>
#include <math.h>

#define DEPTH   5
#define HIDDEN  128
#define CODE    400
#define NFREQ   9
#define BATCH   8
#define NPTS    262144
#define PTSB    64
#define BLOCK   256

typedef __attribute__((ext_vector_type(8))) short sh8;
typedef __attribute__((ext_vector_type(4))) float f32x4;
typedef __attribute__((ext_vector_type(4))) uint  u32x4;

union U8 { u32x4 u; sh8 s; };

struct CoefTab { float c[54]; };   // [s][yk] SH normalization, host-computed

__device__ __forceinline__ ushort f2bf(float f) {   // round-to-nearest-even
    union { float f; uint u; } v; v.f = f;
    uint r = v.u + 0x7fffu + ((v.u >> 16) & 1u);
    return (ushort)(r >> 16);
}

// ---------------------------------------------------------------------------
// Prep.  cterm[i][b][h] = a·Wcode + bcode + bfwd.
// wfB: filter B-frags (K=32): (kq=0,j)=w[y_j]; (1,0)=(1,1)=w[y8]; (1,2)=bftr;
//      (2,j)=w[y_j] dup (pairs with yl); t=0 trunc-hi / t=1 rounded-lo.
// gwB: Wfwd B-frags [layer][kq][nt(8)][img][lane][j], trunc-hi / rounded-lo.
// ---------------------------------------------------------------------------
__global__ void sinr_prep(const float* __restrict__ a,
                          const float* __restrict__ Wcode,
                          const float* __restrict__ bcode,
                          const float* __restrict__ bfwd,
                          const float* __restrict__ Wftr,
                          const float* __restrict__ bftr,
                          const float* __restrict__ Wfwd,
                          CoefTab ct,
                          float* __restrict__ cterm,
                          ushort* __restrict__ wfB,
                          ushort* __restrict__ gwB) {
    int blk = blockIdx.x, tid = threadIdx.x;
    if (blk < DEPTH * BATCH) {
        if (tid < HIDDEN) {
            int i = blk / BATCH, b = blk % BATCH, h = tid;
            const float* ar = a + b * CODE;
            const float* wr = Wcode + (i * HIDDEN + h) * CODE;
            float acc = bcode[i * HIDDEN + h] + bfwd[i * HIDDEN + h];
            for (int c = 0; c < CODE; c += 4) {
                float4 av = *(const float4*)(ar + c);
                float4 wv = *(const float4*)(wr + c);
                acc = fmaf(av.x, wv.x, acc);
                acc = fmaf(av.y, wv.y, acc);
                acc = fmaf(av.z, wv.z, acc);
                acc = fmaf(av.w, wv.w, acc);
            }
            cterm[(i * BATCH + b) * HIDDEN + h] = acc;
        }
    } else if (blk < DEPTH * BATCH + 192) {
        int e = (blk - DEPTH * BATCH) * BLOCK + tid;     // < 49152
        int j    = e & 7;
        int lane = (e >> 3) & 63;
        int t    = (e >> 9) & 1;
        int nt   = (e >> 10) & 7;
        int s    = e >> 13;                               // 0..5
        int g  = nt * 16 + (lane & 15);
        int kq = lane >> 4;
        float v = 0.0f;
        if (kq == 0 || kq == 2) {
            v = ct.c[s * 9 + j] * Wftr[(s * HIDDEN + g) * NFREQ + j];
        } else if (kq == 1) {
            if (j == 0 || j == 1)
                v = ct.c[s * 9 + 8] * Wftr[(s * HIDDEN + g) * NFREQ + 8];
            else if (j == 2)
                v = bftr[s * HIDDEN + g];
        }
        uint u = __float_as_uint(v);
        float rf = v - __uint_as_float(u & 0xFFFF0000u);
        wfB[e] = t ? f2bf(rf) : (ushort)(u >> 16);
    } else {
        int e = (blk - DEPTH * BATCH - 192) * BLOCK + tid;  // < 163840
        if (e < DEPTH * 4 * 8 * 2 * 512) {
            int j     = e & 7;
            int lane  = (e >> 3) & 63;
            int img   = (e >> 9) & 1;
            int nt    = (e >> 10) & 7;
            int kq    = (e >> 13) & 3;
            int layer = e >> 15;
            int g = nt * 16 + (lane & 15);
            int h = kq * 32 + (lane >> 4) * 8 + j;
            float v = Wfwd[(layer * HIDDEN + g) * HIDDEN + h];
            uint u = __float_as_uint(v);
            float rf = v - __uint_as_float(u & 0xFFFF0000u);
            gwB[e] = img ? f2bf(rf) : (ushort)(u >> 16);
        }
    }
}

// ---------------------------------------------------------------------------
// Main. 4 waves; wave w owns cols w*32..+31 (2 N-tiles), all 64 rows, 2
// barriers/layer. z packed one uint/elem (hi bf16 low16, lo high16).
// Swizzle (16B-granular): word-chunk c = h>>2, phys = c ^ (row&31),
// word = row*128 + phys*4 + (h&3). A-reads spread all 32 banks (8 cyc/b128).
// ---------------------------------------------------------------------------
__global__ __launch_bounds__(BLOCK, 3)
void sinr_main(const float* __restrict__ x,
               const ushort* __restrict__ wfB,
               const ushort* __restrict__ gwB,
               const float* __restrict__ cterm,
               const float* __restrict__ Wout,
               const float* __restrict__ boutp,
               float* __restrict__ out,
               float* __restrict__ out_x) {
    __shared__ __align__(16) uint   zz[PTSB * HIDDEN];       // 32 KB
    __shared__ __align__(16) ushort ypk[6 * 3 * PTSB * 8];   // 18 KB
    __shared__ __align__(16) ushort zrow[8];
    __shared__ float psum[BLOCK];

    const int tid  = threadIdx.x;
    const int lane = tid & 63;
    const int w    = tid >> 6;
    const int l15  = lane & 15, lq = lane >> 4;
    const int p0   = blockIdx.x * PTSB;
    const int b    = p0 >> 15;
    const uint SEL_LL = 0x05040100u, SEL_HH = 0x07060302u;

    if (tid < 2 * PTSB) out_x[p0 * 2 + tid] = x[p0 * 2 + tid];
    if (tid >= 64 && tid < 72) zrow[tid - 64] = 0;

    // ---- harmonics + y A-fragments (hi / special / lo blocks per s) --------
    if (tid < PTSB) {
        float th = x[(p0 + tid) * 2 + 0];
        float ph = x[(p0 + tid) * 2 + 1];
        float c  = cosf(ph);
        float somx2 = sqrtf(fmaxf(1.0f - c * c, 0.0f));
        float s1, c1;
        sincosf(th, &s1, &c1);
        float ctab[5], stab[5];
        ctab[0] = 1.0f; stab[0] = 0.0f;
        ctab[1] = c1;   stab[1] = s1;
#pragma unroll
        for (int k = 2; k <= 4; ++k) {
            ctab[k] = ctab[k - 1] * c1 - stab[k - 1] * s1;
            stab[k] = stab[k - 1] * c1 + ctab[k - 1] * s1;
        }
        float P[5][6];
        float pmm = 1.0f;
#pragma unroll
        for (int am = 0; am <= 4; ++am) {
            if (am > 0) pmm *= -(2.0f * am - 1.0f) * somx2;
            float pm2 = pmm;
            float pm1 = c * (2.0f * am + 1.0f) * pmm;
            P[am][0] = pm2;
            P[am][1] = pm1;
#pragma unroll
            for (int s = 2; s < 6; ++s) {
                int l = am + s;
                float pl = ((2.0f * l - 1.0f) * c * pm1
                            - (float)(l + am - 1) * pm2) / (float)(l - am);
                P[am][s] = pl;
                pm2 = pm1;
                pm1 = pl;
            }
        }
#pragma unroll
        for (int s = 0; s < 6; ++s) {
            ushort yh[9], yl[9];
#pragma unroll
            for (int mm = -4; mm <= 4; ++mm) {
                int am = mm < 0 ? -mm : mm;
                float trig = (mm > 0) ? ctab[am] : ((mm < 0) ? stab[am] : 1.0f);
                float yv = P[am][s] * trig;
                uint u = __float_as_uint(yv);
                yh[mm + 4] = (ushort)(u >> 16);
                float rf = yv - __uint_as_float(u & 0xFFFF0000u);
                yl[mm + 4] = (ushort)(__float_as_uint(rf) >> 16);
            }
            sh8 k0, k1, k2;
#pragma unroll
            for (int j = 0; j < 8; ++j) { k0[j] = (short)yh[j]; k2[j] = (short)yl[j]; }
            k1[0] = (short)yh[8]; k1[1] = (short)yl[8]; k1[2] = (short)0x3F80;
            k1[3] = 0; k1[4] = 0; k1[5] = 0; k1[6] = 0; k1[7] = 0;
            int off = ((s * 3) * PTSB + tid) * 8;
            *(sh8*)&ypk[off]                = k0;
            *(sh8*)&ypk[off + PTSB * 8]     = k1;
            *(sh8*)&ypk[off + 2 * PTSB * 8] = k2;
        }
    }
    __syncthreads();

    auto packw = [&](float val) -> uint {       // trunc-hi | trunc-lo<<16
        uint u = __float_as_uint(val);
        float rf = val - __uint_as_float(u & 0xFFFF0000u);
        return __builtin_amdgcn_perm(__float_as_uint(rf), u, SEL_HH);
    };
    // write: row = mt*16+lq*4+r, h = (w*2+nt)*16+l15
    auto zidx_w = [&](int mt, int nt, int r) -> int {
        int row = mt * 16 + lq * 4 + r;
        int c   = (w * 2 + nt) * 4 + (l15 >> 2);
        return row * HIDDEN + ((c ^ (row & 31)) << 2) + (l15 & 3);
    };
    // F phase for shift s -> facc[4][2]
    auto fphase = [&](int s, f32x4 (*facc)[2]) {
        sh8 wb1[2], wb2[2];
#pragma unroll
        for (int nt = 0; nt < 2; ++nt) {
            const ushort* wp = wfB + s * 8192 + (w * 2 + nt) * 1024 + lane * 8;
            wb1[nt] = *(const sh8*)wp;
            wb2[nt] = *(const sh8*)(wp + 512);
        }
#pragma unroll
        for (int mt = 0; mt < 4; ++mt) {
            const ushort* ya = (lq < 3)
                ? &ypk[(((s * 3 + lq) * PTSB) + mt * 16 + l15) * 8]
                : &zrow[0];
            sh8 yf = *(const sh8*)ya;
#pragma unroll
            for (int nt = 0; nt < 2; ++nt) {
                f32x4 t = (f32x4){0.f, 0.f, 0.f, 0.f};
                t = __builtin_amdgcn_mfma_f32_16x16x32_bf16(yf, wb1[nt], t, 0, 0, 0);
                t = __builtin_amdgcn_mfma_f32_16x16x32_bf16(yf, wb2[nt], t, 0, 0, 0);
                facc[mt][nt] = t;
            }
        }
    };

    // ---- z init: z0 = F(sft=0) ---------------------------------------------
    {
        f32x4 f0[4][2];
        fphase(0, f0);
#pragma unroll
        for (int mt = 0; mt < 4; ++mt)
#pragma unroll
            for (int nt = 0; nt < 2; ++nt)
#pragma unroll
                for (int r = 0; r < 4; ++r)
                    zz[zidx_w(mt, nt, r)] = packw(f0[mt][nt][r]);
    }
    __syncthreads();

    // ---- 5 layers (2 barriers/layer) ---------------------------------------
    for (int layer = 0; layer < DEPTH; ++layer) {
        f32x4 facc[4][2];
        fphase(layer + 1, facc);

        float ctv[2];
#pragma unroll
        for (int nt = 0; nt < 2; ++nt)
            ctv[nt] = cterm[(layer * BATCH + b) * HIDDEN + (w * 2 + nt) * 16 + l15];

        f32x4 acc[4][2];
#pragma unroll
        for (int mt = 0; mt < 4; ++mt)
#pragma unroll
            for (int nt = 0; nt < 2; ++nt)
                acc[mt][nt] = (f32x4){0.f, 0.f, 0.f, 0.f};

        // rolling register prefetch of B fragments
        const ushort* gbase = gwB + layer * 4 * 8192;
        sh8 pbh[2][2], pbl[2][2];
#pragma unroll
        for (int nt = 0; nt < 2; ++nt) {
            const ushort* gp = gbase + (w * 2 + nt) * 1024 + lane * 8;
            pbh[0][nt] = *(const sh8*)gp;
            pbl[0][nt] = *(const sh8*)(gp + 512);
        }
#pragma unroll
        for (int kq = 0; kq < 4; ++kq) {
            const int cur = kq & 1, nxt = cur ^ 1;
            if (kq < 3) {
                const ushort* gp = gbase + (kq + 1) * 8192 + lane * 8;
#pragma unroll
                for (int nt = 0; nt < 2; ++nt) {
                    pbh[nxt][nt] = *(const sh8*)(gp + (w * 2 + nt) * 1024);
                    pbl[nxt][nt] = *(const sh8*)(gp + (w * 2 + nt) * 1024 + 512);
                }
            }
            // batched A reads (8 outstanding b128s)
            u32x4 A0[4], A1[4];
#pragma unroll
            for (int mt = 0; mt < 4; ++mt) {
                int row = mt * 16 + l15;
                int sw = row & 31;
                int c0 = kq * 8 + lq * 2;
                A0[mt] = *(const u32x4*)&zz[row * HIDDEN + ((c0 ^ sw) << 2)];
                A1[mt] = *(const u32x4*)&zz[row * HIDDEN + (((c0 + 1) ^ sw) << 2)];
            }
#pragma unroll
            for (int mt = 0; mt < 4; ++mt) {
                U8 hv, lv;
                hv.u.x = __builtin_amdgcn_perm(A0[mt].y, A0[mt].x, SEL_LL);
                hv.u.y = __builtin_amdgcn_perm(A0[mt].w, A0[mt].z, SEL_LL);
                hv.u.z = __builtin_amdgcn_perm(A1[mt].y, A1[mt].x, SEL_LL);
                hv.u.w = __builtin_amdgcn_perm(A1[mt].w, A1[mt].z, SEL_LL);
                lv.u.x = __builtin_amdgcn_perm(A0[mt].y, A0[mt].x, SEL_HH);
                lv.u.y = __builtin_amdgcn_perm(A0[mt].w, A0[mt].z, SEL_HH);
                lv.u.z = __builtin_amdgcn_perm(A1[mt].y, A1[mt].x, SEL_HH);
                lv.u.w = __builtin_amdgcn_perm(A1[mt].w, A1[mt].z, SEL_HH);
                sh8 ah = hv.s, al = lv.s;
#pragma unroll
                for (int nt = 0; nt < 2; ++nt) {
                    acc[mt][nt] = __builtin_amdgcn_mfma_f32_16x16x32_bf16(ah, pbh[cur][nt], acc[mt][nt], 0, 0, 0);
                    acc[mt][nt] = __builtin_amdgcn_mfma_f32_16x16x32_bf16(al, pbh[cur][nt], acc[mt][nt], 0, 0, 0);
                    acc[mt][nt] = __builtin_amdgcn_mfma_f32_16x16x32_bf16(ah, pbl[cur][nt], acc[mt][nt], 0, 0, 0);
                }
            }
        }
        __syncthreads();   // all z reads complete before overwrite

        // epilogue: z_next = (acc + ct) * F
#pragma unroll
        for (int mt = 0; mt < 4; ++mt)
#pragma unroll
            for (int nt = 0; nt < 2; ++nt)
#pragma unroll
                for (int r = 0; r < 4; ++r)
                    zz[zidx_w(mt, nt, r)] =
                        packw((acc[mt][nt][r] + ctv[nt]) * facc[mt][nt][r]);
        __syncthreads();   // all writes visible before next layer's reads
    }

    // ---- final: out[p] = (zh+zl) · Wout + bout ------------------------------
    {
        int p = tid & 63, qd = tid >> 6;
        float accf = 0.0f;
#pragma unroll
        for (int cc = 0; cc < 4; ++cc) {
            int hc = qd * 4 + cc;
            int c0 = hc * 2;
            u32x4 a0 = *(const u32x4*)&zz[p * HIDDEN + ((c0 ^ (p & 31)) << 2)];
            u32x4 a1 = *(const u32x4*)&zz[p * HIDDEN + (((c0 + 1) ^ (p & 31)) << 2)];
            uint uu[8] = {a0.x, a0.y, a0.z, a0.w, a1.x, a1.y, a1.z, a1.w};
            const float* wp = Wout + hc * 8;
#pragma unroll
            for (int j = 0; j < 8; ++j) {
                float hi = __uint_as_float(uu[j] << 16);
                float lo = __uint_as_float(uu[j] & 0xFFFF0000u);
                accf = fmaf(hi + lo, wp[j], accf);
            }
        }
        psum[qd * 64 + p] = accf;
    }
    __syncthreads();
    if (tid < PTSB) {
        out[p0 + tid] = boutp[0] + psum[tid] + psum[64 + tid]
                                 + psum[128 + tid] + psum[192 + tid];
    }
}

// ---------------------------------------------------------------------------
extern "C" void kernel_launch(void* const* d_in, const int* in_sizes, int n_in,
                              void* d_out, int out_size, void* d_ws, size_t ws_size,
                              hipStream_t stream) {
    (void)in_sizes; (void)n_in; (void)out_size; (void)ws_size;
    const float* x     = (const float*)d_in[0];
    const float* a     = (const float*)d_in[1];
    const float* Wftr  = (const float*)d_in[2];
    const float* bftr  = (const float*)d_in[3];
    const float* Wfwd  = (const float*)d_in[4];
    const float* bfwd  = (const float*)d_in[5];
    const float* Wcode = (const float*)d_in[6];
    const float* bcode = (const float*)d_in[7];
    const float* Wout  = (const float*)d_in[8];
    const float* bout  = (const float*)d_in[9];

    float* out   = (float*)d_out;                    // [B*N]
    float* out_x = out + NPTS;                       // [B*N*2]
    float*  cterm = (float*)d_ws;                    // 5120 floats
    ushort* wfB = (ushort*)(cterm + DEPTH * BATCH * HIDDEN);  // 49152 ushorts
    ushort* gwB = wfB + 49152;                                // 163840 ushorts

    // SH normalization coefficients on host (deterministic per call)
    CoefTab ct;
    for (int s = 0; s < 6; ++s)
        for (int yk = 0; yk < 9; ++yk) {
            int mm = yk - 4, am = mm < 0 ? -mm : mm, l = am + s;
            double ratio = 1.0;
            for (int q = l - am + 1; q <= l + am; ++q) ratio *= (double)q;
            double norm = sqrt((2.0 * l + 1.0) / (4.0 * M_PI * ratio));
            double cf = (mm == 0) ? norm : ((am & 1) ? -1.0 : 1.0) * sqrt(2.0) * norm;
            ct.c[s * 9 + yk] = (float)cf;
        }

    int nprep = DEPTH * BATCH + 192 + 640;
    sinr_prep<<<nprep, BLOCK, 0, stream>>>(a, Wcode, bcode, bfwd, Wftr, bftr,
                                           Wfwd, ct, cterm, wfB, gwB);
    sinr_main<<<NPTS / PTSB, BLOCK, 0, stream>>>(
        x, wfB, gwB, cterm, Wout, bout, out, out_x);
}

// Round 9
// 222.475 us; speedup vs baseline: 1.0447x; 1.0447x over previous
//
#include <hip/hip_runtime.h>
#include <math.h>

#define DEPTH   5
#define HIDDEN  128
#define CODE    400
#define NFREQ   9
#define BATCH   8
#define NPTS    262144
#define PTSB    64
#define BLOCK   256

typedef __attribute__((ext_vector_type(8))) short sh8;
typedef __attribute__((ext_vector_type(4))) float f32x4;
typedef __attribute__((ext_vector_type(4))) uint  u32x4;

struct CoefTab { float c[54]; };   // [s][yk] SH normalization, host-computed

__device__ __forceinline__ ushort f2bf(float f) {   // round-to-nearest-even
    union { float f; uint u; } v; v.f = f;
    uint r = v.u + 0x7fffu + ((v.u >> 16) & 1u);
    return (ushort)(r >> 16);
}

// ---------------------------------------------------------------------------
// Prep (identical to R6/R7 proven version).
// cterm[i][b][h] = a·Wcode + bcode + bfwd.
// wfB: filter B-frags (K=32): (kq=0,j)=w[y_j]; (1,0)=(1,1)=w[y8]; (1,2)=bftr;
//      (2,j)=w[y_j] dup (pairs with yl); t=0 trunc-hi / t=1 rounded-lo.
// gwB: Wfwd B-frags [layer][kq][nt(8)][img][lane][j], trunc-hi / rounded-lo.
// ---------------------------------------------------------------------------
__global__ void sinr_prep(const float* __restrict__ a,
                          const float* __restrict__ Wcode,
                          const float* __restrict__ bcode,
                          const float* __restrict__ bfwd,
                          const float* __restrict__ Wftr,
                          const float* __restrict__ bftr,
                          const float* __restrict__ Wfwd,
                          CoefTab ct,
                          float* __restrict__ cterm,
                          ushort* __restrict__ wfB,
                          ushort* __restrict__ gwB) {
    int blk = blockIdx.x, tid = threadIdx.x;
    if (blk < DEPTH * BATCH) {
        if (tid < HIDDEN) {
            int i = blk / BATCH, b = blk % BATCH, h = tid;
            const float* ar = a + b * CODE;
            const float* wr = Wcode + (i * HIDDEN + h) * CODE;
            float acc = bcode[i * HIDDEN + h] + bfwd[i * HIDDEN + h];
            for (int c = 0; c < CODE; c += 4) {
                float4 av = *(const float4*)(ar + c);
                float4 wv = *(const float4*)(wr + c);
                acc = fmaf(av.x, wv.x, acc);
                acc = fmaf(av.y, wv.y, acc);
                acc = fmaf(av.z, wv.z, acc);
                acc = fmaf(av.w, wv.w, acc);
            }
            cterm[(i * BATCH + b) * HIDDEN + h] = acc;
        }
    } else if (blk < DEPTH * BATCH + 192) {
        int e = (blk - DEPTH * BATCH) * BLOCK + tid;     // < 49152
        int j    = e & 7;
        int lane = (e >> 3) & 63;
        int t    = (e >> 9) & 1;
        int nt   = (e >> 10) & 7;
        int s    = e >> 13;                               // 0..5
        int g  = nt * 16 + (lane & 15);
        int kq = lane >> 4;
        float v = 0.0f;
        if (kq == 0 || kq == 2) {
            v = ct.c[s * 9 + j] * Wftr[(s * HIDDEN + g) * NFREQ + j];
        } else if (kq == 1) {
            if (j == 0 || j == 1)
                v = ct.c[s * 9 + 8] * Wftr[(s * HIDDEN + g) * NFREQ + 8];
            else if (j == 2)
                v = bftr[s * HIDDEN + g];
        }
        uint u = __float_as_uint(v);
        float rf = v - __uint_as_float(u & 0xFFFF0000u);
        wfB[e] = t ? f2bf(rf) : (ushort)(u >> 16);
    } else {
        int e = (blk - DEPTH * BATCH - 192) * BLOCK + tid;  // < 163840
        if (e < DEPTH * 4 * 8 * 2 * 512) {
            int j     = e & 7;
            int lane  = (e >> 3) & 63;
            int img   = (e >> 9) & 1;
            int nt    = (e >> 10) & 7;
            int kq    = (e >> 13) & 3;
            int layer = e >> 15;
            int g = nt * 16 + (lane & 15);
            int h = kq * 32 + (lane >> 4) * 8 + j;
            float v = Wfwd[(layer * HIDDEN + g) * HIDDEN + h];
            uint u = __float_as_uint(v);
            float rf = v - __uint_as_float(u & 0xFFFF0000u);
            gwB[e] = img ? f2bf(rf) : (ushort)(u >> 16);
        }
    }
}

// ---------------------------------------------------------------------------
// Main. 4 waves; wave w owns cols w*32..+31 (2 N-tiles), all 64 rows, 2
// barriers/layer (R6-proven skeleton). z stored as TWO separate bf16 images
// zh16/zl16 (16 KB each) -> A-fragments are direct ds_read_b128, no perms.
// Swizzle (element space, both arrays): chunk = h>>3, phys = chunk^(row&15),
// idx = row*128 + phys*8 + (h&7). A-reads uniform over all 8 bank groups.
// ---------------------------------------------------------------------------
__global__ __launch_bounds__(BLOCK, 3)
void sinr_main(const float* __restrict__ x,
               const ushort* __restrict__ wfB,
               const ushort* __restrict__ gwB,
               const float* __restrict__ cterm,
               const float* __restrict__ Wout,
               const float* __restrict__ boutp,
               float* __restrict__ out,
               float* __restrict__ out_x) {
    __shared__ __align__(16) ushort zh16[PTSB * HIDDEN];     // 16 KB
    __shared__ __align__(16) ushort zl16[PTSB * HIDDEN];     // 16 KB
    __shared__ __align__(16) ushort ypk[6 * 3 * PTSB * 8];   // 18 KB
    __shared__ __align__(16) ushort zrow[8];

    const int tid  = threadIdx.x;
    const int lane = tid & 63;
    const int w    = tid >> 6;
    const int l15  = lane & 15, lq = lane >> 4;
    const int p0   = blockIdx.x * PTSB;
    const int b    = p0 >> 15;

    if (tid < 2 * PTSB) out_x[p0 * 2 + tid] = x[p0 * 2 + tid];
    if (tid < 8) zrow[tid] = 0;

    // ---- harmonics, distributed: every wave computes the full P/trig table
    // for point p=lane; wave w packs/stores shifts s in {w, w+4} -------------
    {
        float th = x[(p0 + lane) * 2 + 0];
        float ph = x[(p0 + lane) * 2 + 1];
        float c  = cosf(ph);
        float somx2 = sqrtf(fmaxf(1.0f - c * c, 0.0f));
        float s1, c1;
        sincosf(th, &s1, &c1);
        float ctab[5], stab[5];
        ctab[0] = 1.0f; stab[0] = 0.0f;
        ctab[1] = c1;   stab[1] = s1;
#pragma unroll
        for (int k = 2; k <= 4; ++k) {
            ctab[k] = ctab[k - 1] * c1 - stab[k - 1] * s1;
            stab[k] = stab[k - 1] * c1 + ctab[k - 1] * s1;
        }
        float P[5][6];
        float pmm = 1.0f;
#pragma unroll
        for (int am = 0; am <= 4; ++am) {
            if (am > 0) pmm *= -(2.0f * am - 1.0f) * somx2;
            float pm2 = pmm;
            float pm1 = c * (2.0f * am + 1.0f) * pmm;
            P[am][0] = pm2;
            P[am][1] = pm1;
#pragma unroll
            for (int s = 2; s < 6; ++s) {
                int l = am + s;
                float pl = ((2.0f * l - 1.0f) * c * pm1
                            - (float)(l + am - 1) * pm2) / (float)(l - am);
                P[am][s] = pl;
                pm2 = pm1;
                pm1 = pl;
            }
        }
        for (int s = w; s < 6; s += 4) {
            ushort yh[9], yl[9];
#pragma unroll
            for (int mm = -4; mm <= 4; ++mm) {
                int am = mm < 0 ? -mm : mm;
                float trig = (mm > 0) ? ctab[am] : ((mm < 0) ? stab[am] : 1.0f);
                float yv = P[am][s] * trig;
                uint u = __float_as_uint(yv);
                yh[mm + 4] = (ushort)(u >> 16);
                float rf = yv - __uint_as_float(u & 0xFFFF0000u);
                yl[mm + 4] = (ushort)(__float_as_uint(rf) >> 16);
            }
            sh8 k0, k1, k2;
#pragma unroll
            for (int j = 0; j < 8; ++j) { k0[j] = (short)yh[j]; k2[j] = (short)yl[j]; }
            k1[0] = (short)yh[8]; k1[1] = (short)yl[8]; k1[2] = (short)0x3F80;
            k1[3] = 0; k1[4] = 0; k1[5] = 0; k1[6] = 0; k1[7] = 0;
            int off = ((s * 3) * PTSB + lane) * 8;
            *(sh8*)&ypk[off]                = k0;
            *(sh8*)&ypk[off + PTSB * 8]     = k1;
            *(sh8*)&ypk[off + 2 * PTSB * 8] = k2;
        }
    }
    __syncthreads();

    // z store: row = mt*16+lq*4+r, col h = (w*2+nt)*16+l15; split-bf16 trunc
    auto zstore = [&](int mt, int nt, int r, float val) {
        int row = mt * 16 + lq * 4 + r;
        int hh  = (w * 2 + nt) * 16 + l15;
        int idx = row * HIDDEN + ((((hh >> 3) ^ (row & 15))) << 3) + (hh & 7);
        uint u = __float_as_uint(val);
        zh16[idx] = (ushort)(u >> 16);
        float rf = val - __uint_as_float(u & 0xFFFF0000u);
        zl16[idx] = (ushort)(__float_as_uint(rf) >> 16);
    };
    // F phase for shift s -> facc[4][2] (2 MFMAs per tile, R6-proven)
    auto fphase = [&](int s, f32x4 (*facc)[2]) {
        sh8 wb1[2], wb2[2];
#pragma unroll
        for (int nt = 0; nt < 2; ++nt) {
            const ushort* wp = wfB + s * 8192 + (w * 2 + nt) * 1024 + lane * 8;
            wb1[nt] = *(const sh8*)wp;
            wb2[nt] = *(const sh8*)(wp + 512);
        }
#pragma unroll
        for (int mt = 0; mt < 4; ++mt) {
            const ushort* ya = (lq < 3)
                ? &ypk[(((s * 3 + lq) * PTSB) + mt * 16 + l15) * 8]
                : &zrow[0];
            sh8 yf = *(const sh8*)ya;
#pragma unroll
            for (int nt = 0; nt < 2; ++nt) {
                f32x4 t = (f32x4){0.f, 0.f, 0.f, 0.f};
                t = __builtin_amdgcn_mfma_f32_16x16x32_bf16(yf, wb1[nt], t, 0, 0, 0);
                t = __builtin_amdgcn_mfma_f32_16x16x32_bf16(yf, wb2[nt], t, 0, 0, 0);
                facc[mt][nt] = t;
            }
        }
    };

    // ---- z init: z0 = F(sft=0) ---------------------------------------------
    {
        f32x4 f0[4][2];
        fphase(0, f0);
#pragma unroll
        for (int mt = 0; mt < 4; ++mt)
#pragma unroll
            for (int nt = 0; nt < 2; ++nt)
#pragma unroll
                for (int r = 0; r < 4; ++r)
                    zstore(mt, nt, r, f0[mt][nt][r]);
    }
    __syncthreads();

    // ---- 5 layers (2 barriers/layer) ---------------------------------------
    for (int layer = 0; layer < DEPTH; ++layer) {
        f32x4 facc[4][2];
        fphase(layer + 1, facc);

        float ctv[2];
#pragma unroll
        for (int nt = 0; nt < 2; ++nt)
            ctv[nt] = cterm[(layer * BATCH + b) * HIDDEN + (w * 2 + nt) * 16 + l15];

        f32x4 acc[4][2];
#pragma unroll
        for (int mt = 0; mt < 4; ++mt)
#pragma unroll
            for (int nt = 0; nt < 2; ++nt)
                acc[mt][nt] = (f32x4){0.f, 0.f, 0.f, 0.f};

#pragma unroll
        for (int kq = 0; kq < 4; ++kq) {
            const ushort* gp = gwB + (layer * 4 + kq) * 8192 + lane * 8;
            sh8 bh0 = *(const sh8*)(gp + (w * 2 + 0) * 1024);
            sh8 bl0 = *(const sh8*)(gp + (w * 2 + 0) * 1024 + 512);
            sh8 bh1 = *(const sh8*)(gp + (w * 2 + 1) * 1024);
            sh8 bl1 = *(const sh8*)(gp + (w * 2 + 1) * 1024 + 512);
#pragma unroll
            for (int mt = 0; mt < 4; ++mt) {
                int row  = mt * 16 + l15;
                int base = row * HIDDEN + (((kq * 4 + lq) ^ l15) << 3);
                sh8 ah = *(const sh8*)&zh16[base];
                sh8 al = *(const sh8*)&zl16[base];
                acc[mt][0] = __builtin_amdgcn_mfma_f32_16x16x32_bf16(ah, bh0, acc[mt][0], 0, 0, 0);
                acc[mt][0] = __builtin_amdgcn_mfma_f32_16x16x32_bf16(al, bh0, acc[mt][0], 0, 0, 0);
                acc[mt][0] = __builtin_amdgcn_mfma_f32_16x16x32_bf16(ah, bl0, acc[mt][0], 0, 0, 0);
                acc[mt][1] = __builtin_amdgcn_mfma_f32_16x16x32_bf16(ah, bh1, acc[mt][1], 0, 0, 0);
                acc[mt][1] = __builtin_amdgcn_mfma_f32_16x16x32_bf16(al, bh1, acc[mt][1], 0, 0, 0);
                acc[mt][1] = __builtin_amdgcn_mfma_f32_16x16x32_bf16(ah, bl1, acc[mt][1], 0, 0, 0);
            }
        }
        __syncthreads();   // all z reads complete before overwrite

        // epilogue: z_next = (acc + ct) * F
#pragma unroll
        for (int mt = 0; mt < 4; ++mt)
#pragma unroll
            for (int nt = 0; nt < 2; ++nt)
#pragma unroll
                for (int r = 0; r < 4; ++r)
                    zstore(mt, nt, r, (acc[mt][nt][r] + ctv[nt]) * facc[mt][nt][r]);
        __syncthreads();   // writes visible before next layer's reads
    }

    // ---- final: out[p] = (zh+zl) · Wout + bout (psum overlays dead ypk) ----
    float* psum = (float*)ypk;
    {
        int p = lane, qd = w;
        float accf = 0.0f;
#pragma unroll
        for (int cc = 0; cc < 4; ++cc) {
            int chunk = qd * 4 + cc;
            int base  = p * HIDDEN + ((chunk ^ (p & 15)) << 3);
            u32x4 hv = *(const u32x4*)&zh16[base];
            u32x4 lv = *(const u32x4*)&zl16[base];
            uint uh[4] = {hv.x, hv.y, hv.z, hv.w};
            uint ul[4] = {lv.x, lv.y, lv.z, lv.w};
            const float* wp = Wout + chunk * 8;
#pragma unroll
            for (int q2 = 0; q2 < 4; ++q2) {
                float a0 = __uint_as_float(uh[q2] << 16)
                         + __uint_as_float(ul[q2] << 16);
                float a1 = __uint_as_float(uh[q2] & 0xFFFF0000u)
                         + __uint_as_float(ul[q2] & 0xFFFF0000u);
                accf = fmaf(a0, wp[q2 * 2], accf);
                accf = fmaf(a1, wp[q2 * 2 + 1], accf);
            }
        }
        psum[qd * 64 + p] = accf;
    }
    __syncthreads();
    if (tid < PTSB) {
        out[p0 + tid] = boutp[0] + psum[tid] + psum[64 + tid]
                                 + psum[128 + tid] + psum[192 + tid];
    }
}

// ---------------------------------------------------------------------------
extern "C" void kernel_launch(void* const* d_in, const int* in_sizes, int n_in,
                              void* d_out, int out_size, void* d_ws, size_t ws_size,
                              hipStream_t stream) {
    (void)in_sizes; (void)n_in; (void)out_size; (void)ws_size;
    const float* x     = (const float*)d_in[0];
    const float* a     = (const float*)d_in[1];
    const float* Wftr  = (const float*)d_in[2];
    const float* bftr  = (const float*)d_in[3];
    const float* Wfwd  = (const float*)d_in[4];
    const float* bfwd  = (const float*)d_in[5];
    const float* Wcode = (const float*)d_in[6];
    const float* bcode = (const float*)d_in[7];
    const float* Wout  = (const float*)d_in[8];
    const float* bout  = (const float*)d_in[9];

    float* out   = (float*)d_out;                    // [B*N]
    float* out_x = out + NPTS;                       // [B*N*2]
    float*  cterm = (float*)d_ws;                    // 5120 floats
    ushort* wfB = (ushort*)(cterm + DEPTH * BATCH * HIDDEN);  // 49152 ushorts
    ushort* gwB = wfB + 49152;                                // 163840 ushorts

    // SH normalization coefficients on host (deterministic per call)
    CoefTab ct;
    for (int s = 0; s < 6; ++s)
        for (int yk = 0; yk < 9; ++yk) {
            int mm = yk - 4, am = mm < 0 ? -mm : mm, l = am + s;
            double ratio = 1.0;
            for (int q = l - am + 1; q <= l + am; ++q) ratio *= (double)q;
            double norm = sqrt((2.0 * l + 1.0) / (4.0 * M_PI * ratio));
            double cf = (mm == 0) ? norm : ((am & 1) ? -1.0 : 1.0) * sqrt(2.0) * norm;
            ct.c[s * 9 + yk] = (float)cf;
        }

    int nprep = DEPTH * BATCH + 192 + 640;
    sinr_prep<<<nprep, BLOCK, 0, stream>>>(a, Wcode, bcode, bfwd, Wftr, bftr,
                                           Wfwd, ct, cterm, wfB, gwB);
    sinr_main<<<NPTS / PTSB, BLOCK, 0, stream>>>(
        x, wfB, gwB, cterm, Wout, bout, out, out_x);
}